// Round 9
// baseline (4418.213 us; speedup 1.0000x reference)
//
#include <hip/hip_runtime.h>

#define EMB 32
#define HID 256
#define TT  2048

typedef _Float16 f16x8 __attribute__((ext_vector_type(8)));
typedef float    f32x4 __attribute__((ext_vector_type(4)));

// ---- d_ws layout (bytes) ----
// BFRAG: [r 2][w 8][gt 4][s 9][lane 64] f16x8 = 589,824
//        B[k][n] frag for mfma_f32_16x16x32_f16 (layout verified in R8):
//        n = lane&15, k = (lane>>4)*8+e (+32*kstep). Row = gt*256 + r*128 +
//        w*16 + n; global kstep = kslot(s,r) (own/x slots first, peer last).
// BIAS : [r 2][w 8][n 16][gate 4] float = 4,096
// ACK  : int[16]
// FAST : [group 4][member 2][slot 2][dw 1024] = 65,536  (same-XCD L2 mirror)
#define BIAS_OFF 589824
#define ACK_OFF  593920
#define FAST_OFF 594048
// SLOW = d_out, same [group][member][slot][1024 dw] layout (64 KB of its 256 KB).
// Tag protocol (R4-R8-proven): tag ((t+1)>>1)&1 in bit0 of each half, slot
// (t+1)&1; prep inits slot0=tag0, slot1=tag1. Freshness proven by tags, not by
// which cache served the load; 12 stale FAST polls -> sticky escalate to SLOW
// (agent/MALL). Correct under any XCD placement; fast when pair shares an XCD
// (bids g and g+8 under %8 round-robin).

__device__ __forceinline__ float rcp_fast(float v) { return __builtin_amdgcn_rcpf(v); }
__device__ __forceinline__ float sigmoid_fast(float v) { return rcp_fast(1.0f + __expf(-v)); }
__device__ __forceinline__ float tanh_fast(float v) {
    v = fminf(fmaxf(v, -15.0f), 15.0f);
    float e = __expf(2.0f * v);
    return (e - 1.0f) * rcp_fast(e + 1.0f);
}
__device__ __forceinline__ void barrier_lds() {   // no vmcnt drain
    asm volatile("s_waitcnt lgkmcnt(0)\n\ts_barrier" ::: "memory");
}
__device__ __forceinline__ unsigned load_slow(const unsigned* p) {
    return __hip_atomic_load(p, __ATOMIC_RELAXED, __HIP_MEMORY_SCOPE_AGENT);
}
// member-r kstep permutation: s=0 -> x (kstep 0); s in [1,4] -> own-h ksteps;
// s in [5,8] -> peer-h ksteps.
__device__ __forceinline__ int kslot(int s, int r) {
    return s == 0 ? 0 : (s <= 4 ? 4 * r + s : 4 * (1 - r) + (s - 4));
}

// ---- prep: B-fragments, bias+ack, SLOW & FAST tag init. 273 x 256. ----
__global__ void prep_kernel(const float* __restrict__ W_ih,
                            const float* __restrict__ W_hh,
                            const float* __restrict__ b_ih,
                            const float* __restrict__ b_hh,
                            char* __restrict__ ws,
                            unsigned* __restrict__ outw) {
    int bid = blockIdx.x, t = threadIdx.x;
    if (bid < 144) {                          // 36,864 f16x8 fragments
        int gid = bid * 256 + t;
        int lane = gid & 63, rest = gid >> 6;
        int s = rest % 9; rest /= 9;          // [0,64)
        int gt = rest & 3; rest >>= 2;        // [0,16)
        int w = rest & 7, r = rest >> 3;
        int ks = kslot(s, r);
        int row = gt * 256 + r * 128 + w * 16 + (lane & 15);
        f16x8 v;
#pragma unroll
        for (int e = 0; e < 8; ++e) {
            int k = ks * 32 + (lane >> 4) * 8 + e;
            float f = (k < EMB) ? W_ih[row * EMB + k] : W_hh[row * HID + (k - EMB)];
            v[e] = (_Float16)f;
        }
        ((f16x8*)ws)[gid] = v;
    } else if (bid == 144) {                  // bias + ack
        for (int i = t; i < 1024; i += 256) {
            int gate = i & 3, n = (i >> 2) & 15, w = (i >> 6) & 7, r = i >> 9;
            int row = gate * 256 + r * 128 + w * 16 + n;
            ((float*)(ws + BIAS_OFF))[i] = b_ih[row] + b_hh[row];
        }
        if (t < 16) ((int*)(ws + ACK_OFF))[t] = 0;
    } else if (bid < 209) {                   // SLOW tags in d_out: 16,384 dw
        int d = (bid - 145) * 256 + t;
        outw[d] = ((d >> 10) & 1) ? 0x00010001u : 0u;
    } else {                                  // FAST tags in d_ws: 16,384 dw
        int d = (bid - 209) * 256 + t;
        ((unsigned*)(ws + FAST_OFF))[d] = ((d >> 10) & 1) ? 0x00010001u : 0u;
    }
}

// ---- recurrent kernel: 12 blocks (pairs (g, g+8) same-XCD; 4-7 idle), 512 thr ----
// A-image (LDS, dbuf): [chain 16][k 296 pad] fp16. A-frag: lane reads
// A[m=lane&15][k=(lane>>4)*8+e]. C/D: lane holds D[m=4*quad+reg][n=lane&15]
// -> chain = 4*quad+cg, h = r*128 + w*16 + (lane&15). All verified in R8.
__global__ __launch_bounds__(512, 2) void rnn_kernel(const int* __restrict__ x,
                                                     const int* __restrict__ lengths,
                                                     const float* __restrict__ emb,
                                                     char* __restrict__ ws,
                                                     float* __restrict__ out_) {
    const int bid = blockIdx.x;
    if ((bid & 7) >= 4) return;               // XCD-pad blocks
    const int r = bid >> 3, g = bid & 3;

    __shared__ __align__(16) _Float16 Aimg[2][16 * 296];

    const int tid  = threadIdx.x;
    const int w    = tid >> 6;
    const int lane = tid & 63;
    const int n    = lane & 15, quad = lane >> 4;
    const int xc   = tid >> 5, xk = tid & 31;   // x/emb loader role

    // register-resident B fragments: 4 gate-tiles x 9 kslots = 144 regs
    f16x8 B[4][9];
    {
        const f16x8* Bp = (const f16x8*)ws + (size_t)((r * 8 + w) * 4) * 9 * 64;
#pragma unroll
        for (int gt = 0; gt < 4; ++gt)
#pragma unroll
            for (int s = 0; s < 9; ++s) B[gt][s] = Bp[(gt * 9 + s) * 64 + lane];
    }
    const f32x4 bs = *(const f32x4*)(ws + BIAS_OFF + (size_t)((r * 8 + w) * 16 + n) * 16);

    int Lmax = 1, Lc[4];
    for (int c = 0; c < 16; ++c) {
        int v = lengths[g * 16 + c]; v = v < 1 ? 1 : (v > TT ? TT : v);
        if (v > Lmax) Lmax = v;
    }
#pragma unroll
    for (int cg = 0; cg < 4; ++cg) {
        int v = lengths[g * 16 + 4 * quad + cg];
        Lc[cg] = v < 1 ? 1 : (v > TT ? TT : v);
    }

    unsigned* fastG = (unsigned*)(ws + FAST_OFF) + g * 4096;
    unsigned* slowG = (unsigned*)out_ + g * 4096;
    unsigned* mineF = fastG + r * 2048;
    unsigned* mineS = slowG + r * 2048;
    const unsigned* peerF = fastG + (1 - r) * 2048;
    const unsigned* peerS = slowG + (1 - r) * 2048;
    // landing coords for this thread's 2 polled dwords (d = tid and tid+512)
    const int lc0 = tid >> 6, lj0 = tid & 63;        // chain, dword-within-chain
    const int lc1 = 8 + (tid >> 6);
    const int peerKbase = 32 + 128 * (1 - r);

    // init A-images: zero, then x(0)
    for (int i = tid; i < 2 * 16 * 296; i += 512) ((_Float16*)Aimg)[i] = (_Float16)0.0f;
    __syncthreads();
    Aimg[0][xc * 296 + xk] = (_Float16)emb[x[(g * 16 + xc) * TT] * EMB + xk];
    __syncthreads();

    const f32x4 zf = {0.f, 0.f, 0.f, 0.f};
    f32x4 acc[4];
#pragma unroll
    for (int gt = 0; gt < 4; ++gt) acc[gt] = zf;
    // prologue: own/x kslots (s 0..4) for step 0
#pragma unroll
    for (int s = 0; s < 5; ++s) {
        f16x8 af = *(const f16x8*)(Aimg[0] + n * 296 + quad * 8 + kslot(s, r) * 32);
#pragma unroll
        for (int gt = 0; gt < 4; ++gt)
            acc[gt] = __builtin_amdgcn_mfma_f32_16x16x32_f16(af, B[gt][s], acc[gt], 0, 0, 0);
    }

    float cst[4] = {0, 0, 0, 0}, hst[4] = {0, 0, 0, 0};
    int mode = 0;   // 0 = FAST (same-XCD L2), 1 = SLOW (MALL), sticky

#pragma unroll 1
    for (int t = 0; t < Lmax; ++t) {
        const _Float16* __restrict__ Ac = Aimg[t & 1];
        _Float16* __restrict__ An = Aimg[(t + 1) & 1];

        // x(t+1)/emb prefetch (dependent pair; consumed pre-barrier-A)
        int tn = (t + 1 < TT) ? t + 1 : TT - 1;
        float ev = emb[x[(g * 16 + xc) * TT + tn] * EMB + xk];

        // stage1: peer kslots (s 5..8) complete the gates for step t
        {
            f16x8 af[4];
#pragma unroll
            for (int s = 0; s < 4; ++s)
                af[s] = *(const f16x8*)(Ac + n * 296 + quad * 8 + kslot(5 + s, r) * 32);
#pragma unroll
            for (int s = 0; s < 4; ++s)
#pragma unroll
                for (int gt = 0; gt < 4; ++gt)
                    acc[gt] = __builtin_amdgcn_mfma_f32_16x16x32_f16(af[s], B[gt][5 + s], acc[gt], 0, 0, 0);
        }

        // activations + masked state update (lane-local: chain 4*quad+cg)
        const unsigned tg = ((unsigned)(t + 1) >> 1) & 1u;
        const int slot = (t + 1) & 1;
        unsigned hu[4];
#pragma unroll
        for (int cg = 0; cg < 4; ++cg) {
            float iv = sigmoid_fast(acc[0][cg] + bs[0]);
            float fv = sigmoid_fast(acc[1][cg] + bs[1]);
            float gv = tanh_fast(acc[2][cg] + bs[2]);
            float ov = sigmoid_fast(acc[3][cg] + bs[3]);
            float cn = fv * cst[cg] + iv * gv;
            float hn = ov * tanh_fast(cn);
            bool keep = t < Lc[cg];
            cst[cg] = keep ? cn : cst[cg];
            hst[cg] = keep ? hn : hst[cg];
            hu[cg] = (unsigned)__builtin_bit_cast(unsigned short, (_Float16)hst[cg]);
        }

        // pack (n, n+1) via DPP; even-n lanes own the dword
        unsigned pair_[4];
#pragma unroll
        for (int cg = 0; cg < 4; ++cg) {
            unsigned nh = (unsigned)__builtin_amdgcn_mov_dpp((int)hu[cg], 0xB1, 0xF, 0xF, true);
            pair_[cg] = hu[cg] | (nh << 16);
        }
        if (!(lane & 1)) {
#pragma unroll
            for (int cg = 0; cg < 4; ++cg) {
                // dual-publish tagged dword (FAST plain -> XCD L2; SLOW agent -> MALL)
                unsigned ex = (pair_[cg] & 0xFFFEFFFEu) | tg | (tg << 16);
                int d = slot * 1024 + (4 * quad + cg) * 64 + w * 8 + (n >> 1);
                __hip_atomic_store(mineF + d, ex, __ATOMIC_RELAXED, __HIP_MEMORY_SCOPE_WORKGROUP);
                __hip_atomic_store(mineS + d, ex, __ATOMIC_RELAXED, __HIP_MEMORY_SCOPE_AGENT);
                // own h (full precision) into next A-image
                *(unsigned*)(&An[(4 * quad + cg) * 296 + 32 + r * 128 + w * 16 + n]) = pair_[cg];
            }
        }
        An[xc * 296 + xk] = (_Float16)ev;   // x(t+1)
        barrier_lds();   // A

        // first poll (1 dword x 2 per thread = exactly the peer's data)
        const unsigned* pF0 = peerF + slot * 1024 + tid;
        const unsigned* pF1 = pF0 + 512;
        const unsigned* pS0 = peerS + slot * 1024 + tid;
        const unsigned* pS1 = pS0 + 512;
        unsigned d0, d1;
        if (mode) { d0 = load_slow(pS0); d1 = load_slow(pS1); }
        else { d0 = *(volatile const unsigned*)pF0; d1 = *(volatile const unsigned*)pF1; }

        // stage2: own/x kslots (s 0..4) for step t+1, in the exchange shadow
#pragma unroll
        for (int gt = 0; gt < 4; ++gt) acc[gt] = zf;
#pragma unroll
        for (int s = 0; s < 5; ++s) {
            f16x8 af = *(const f16x8*)(An + n * 296 + quad * 8 + kslot(s, r) * 32);
#pragma unroll
            for (int gt = 0; gt < 4; ++gt)
                acc[gt] = __builtin_amdgcn_mfma_f32_16x16x32_f16(af, B[gt][s], acc[gt], 0, 0, 0);
        }

        // finish the spin (sticky FAST->SLOW), land peer h into An
        {
            int tries = 0;
            while (!__all(((d0 & 1u) == tg) && (((d0 >> 16) & 1u) == tg) &&
                          ((d1 & 1u) == tg) && (((d1 >> 16) & 1u) == tg))) {
                ++tries;
                if (mode == 0 && tries > 12) mode = 1;
                if (tries > (1 << 20)) break;
                if (mode) { __builtin_amdgcn_s_sleep(1); d0 = load_slow(pS0); d1 = load_slow(pS1); }
                else { d0 = *(volatile const unsigned*)pF0; d1 = *(volatile const unsigned*)pF1; }
            }
        }
        *(unsigned*)(&An[lc0 * 296 + peerKbase + 2 * lj0]) = d0 & 0xFFFEFFFEu;
        *(unsigned*)(&An[lc1 * 296 + peerKbase + 2 * lj0]) = d1 & 0xFFFEFFFEu;
        barrier_lds();   // B
    }

    // end handshake: partner done reading my exchange regions -> safe to write out
    __syncthreads();
    int* ack = (int*)(ws + ACK_OFF);
    if (tid == 0)
        __hip_atomic_store(&ack[bid], Lmax, __ATOMIC_RELEASE, __HIP_MEMORY_SCOPE_AGENT);
    if (tid == 0) {
        int tries = 0;
        while (__hip_atomic_load(&ack[bid ^ 8], __ATOMIC_ACQUIRE, __HIP_MEMORY_SCOPE_AGENT) != Lmax) {
            if (++tries > (1 << 20)) break;
            __builtin_amdgcn_s_sleep(8);
        }
    }
    __syncthreads();
#pragma unroll
    for (int cg = 0; cg < 4; ++cg)
        out_[(size_t)(g * 16 + 4 * quad + cg) * 256 + r * 128 + w * 16 + n] = hst[cg];
}

extern "C" void kernel_launch(void* const* d_in, const int* in_sizes, int n_in,
                              void* d_out, int out_size, void* d_ws, size_t ws_size,
                              hipStream_t stream) {
    const int*   x       = (const int*)d_in[0];
    const int*   lengths = (const int*)d_in[1];
    const float* emb     = (const float*)d_in[2];
    const float* W_ih    = (const float*)d_in[3];
    const float* W_hh    = (const float*)d_in[4];
    const float* b_ih    = (const float*)d_in[5];
    const float* b_hh    = (const float*)d_in[6];

    prep_kernel<<<273, 256, 0, stream>>>(W_ih, W_hh, b_ih, b_hh,
                                         (char*)d_ws, (unsigned*)d_out);
    rnn_kernel<<<12, 512, 0, stream>>>(x, lengths, emb, (char*)d_ws, (float*)d_out);
}

// Round 10
// 2541.032 us; speedup vs baseline: 1.7387x; 1.7387x over previous
//
#include <hip/hip_runtime.h>
#include <hip/hip_fp16.h>

#define EMB 32
#define HID 256
#define BATCH 64
#define TT  2048

typedef _Float16 half8_t __attribute__((ext_vector_type(8)));
typedef _Float16 half2_t __attribute__((ext_vector_type(2)));

// ---- d_ws layout ----
// W    : [role 2][chunk 36][tid 512] half8   (589,824 B)
//        chunk c=r*9+jj: gate r of h-index Q=128R+(t>>2), lane l=t&3 cols p=8jj+e:
//        p<8 -> x (W_ih col 8l+p); p in [8,40) -> own-h (W_hh 128R+32l+p-8);
//        p in [40,72) -> partner-h (W_hh 128(1-R)+32l+p-40)
// BIAS : [Q 256][r 4] float
// ACK  : int[128]
// FAST : same-XCD exchange mirror, 64 chains x 256 dwords (64 KB)
#define W_BYTES  (2*36*512*16)
#define BIAS_OFF W_BYTES                 // 589824
#define ACK_OFF  (BIAS_OFF + 4096)       // 593920
#define FAST_OFF (ACK_OFF + 1024)        // 594944 (16B aligned)

// ---- exchange protocol (R5-R7 proven) ----
// SLOW = d_out (agent/MALL, always correct). FAST = d_ws mirror (plain stores
// land in producer-XCD L2 via write-through L1; volatile polls bypass L1 and
// hit that L2 when the pair shares an XCD). Freshness proven by per-half tag
// bit, never by which cache served the load; 12 consecutive stale FAST polls
// -> sticky escalation to SLOW. Correct under any XCD placement; fast in the
// expected (b, b+64)->same-XCD round-robin placement (R7: FETCH 22->6 MB
// proved the FAST path live).
// Layout per chain b: dwords [b*256, b*256+256): role R at +128R, slot k&1
// (64 dw). tag ((k>>1)&1) in bit0 of each half. prep inits slot0=tag0,
// slot1=tag1 so first uses never false-match.

__device__ __forceinline__ float fdot2(half2_t a, half2_t b, float c) {
#if __has_builtin(__builtin_amdgcn_fdot2)
    return __builtin_amdgcn_fdot2(a, b, c, false);
#else
    return c + (float)a[0] * (float)b[0] + (float)a[1] * (float)b[1];
#endif
}

__device__ __forceinline__ float dot8(half8_t w, half8_t x, float acc) {
    acc = fdot2(half2_t{w[0], w[1]}, half2_t{x[0], x[1]}, acc);
    acc = fdot2(half2_t{w[2], w[3]}, half2_t{x[2], x[3]}, acc);
    acc = fdot2(half2_t{w[4], w[5]}, half2_t{x[4], x[5]}, acc);
    acc = fdot2(half2_t{w[6], w[7]}, half2_t{x[6], x[7]}, acc);
    return acc;
}

__device__ __forceinline__ float rcp_fast(float v) {
#if __has_builtin(__builtin_amdgcn_rcpf)
    return __builtin_amdgcn_rcpf(v);
#else
    return 1.0f / v;
#endif
}
__device__ __forceinline__ float sigmoid_fast(float v) {
    return rcp_fast(1.0f + __expf(-v));
}
__device__ __forceinline__ float tanh_fast(float v) {
    v = fminf(fmaxf(v, -15.0f), 15.0f);
    float e = __expf(2.0f * v);
    return (e - 1.0f) * rcp_fast(e + 1.0f);
}

// LDS-only barrier: no vmcnt drain — publish stores / polls stay in flight.
__device__ __forceinline__ void barrier_lds() {
    asm volatile("s_waitcnt lgkmcnt(0)\n\ts_barrier" ::: "memory");
}

__device__ __forceinline__ float quad_reduce(float v) {
    int t = __builtin_amdgcn_mov_dpp(__float_as_int(v), 0xB1, 0xF, 0xF, true);
    v += __int_as_float(t);
    t = __builtin_amdgcn_mov_dpp(__float_as_int(v), 0x4E, 0xF, 0xF, true);
    v += __int_as_float(t);
    return v;
}

__device__ __forceinline__ unsigned int load_fast(const unsigned int* p) {
    return *(volatile const unsigned int*)p;      // L1-bypass, L2-hit
}
__device__ __forceinline__ unsigned int load_slow(const unsigned int* p) {
    return __hip_atomic_load(p, __ATOMIC_RELAXED, __HIP_MEMORY_SCOPE_AGENT);
}

__device__ __forceinline__ int gate_row(int r, int Q) {
    return r == 0 ? Q : r == 1 ? 256 + Q : r == 2 ? 512 + Q : 768 + Q;
}

// ---- prep: weights/bias + SLOW (d_out) + FAST (d_ws) tag init ----
// grid 137 x 512: 0..71 weights; 72 bias; 73..104 SLOW init; 105..136 FAST init
__global__ void prep_kernel(const float* __restrict__ W_ih,
                            const float* __restrict__ W_hh,
                            const float* __restrict__ b_ih,
                            const float* __restrict__ b_hh,
                            char* __restrict__ ws,
                            unsigned int* __restrict__ outw) {
    int bid = blockIdx.x, t = threadIdx.x;
    if (bid < 72) {
        int R = bid / 36, c = bid % 36;
        int r = c / 9, jj = c % 9;
        int Q = 128 * R + (t >> 2), l = t & 3;
        int row = gate_row(r, Q);
        half8_t v;
#pragma unroll
        for (int e = 0; e < 8; ++e) {
            int p = 8 * jj + e;
            float f;
            if (p < 8)       f = W_ih[row * EMB + 8 * l + p];
            else if (p < 40) f = W_hh[row * HID + 128 * R + 32 * l + (p - 8)];
            else             f = W_hh[row * HID + 128 * (1 - R) + 32 * l + (p - 40)];
            v[e] = (_Float16)f;
        }
        ((half8_t*)ws)[((size_t)bid) * 512 + t] = v;
    } else if (bid == 72) {
        float* bias = (float*)(ws + BIAS_OFF);
        for (int i = t; i < 1024; i += 512) {
            int Q = i >> 2, r = i & 3;
            int row = gate_row(r, Q);
            bias[i] = b_ih[row] + b_hh[row];
        }
    } else if (bid < 105) {
        int g = (bid - 73) * 512 + t;                  // SLOW tags in d_out
        outw[g] = ((g >> 6) & 1) ? 0x00010001u : 0u;
    } else {
        int g = (bid - 105) * 512 + t;                 // FAST tags in d_ws
        ((unsigned int*)(ws + FAST_OFF))[g] = ((g >> 6) & 1) ? 0x00010001u : 0u;
    }
}

// ---- recurrent kernel: 128 blocks (2 per chain), 512 threads ----
// Software-pipelined: own+x partial dots (jj 0..4) for step t+1 run at the
// tail of iteration t in the exchange-flight shadow; the next token index is
// register-carried so the emb gather is a single independent load at loop top.
__global__ __launch_bounds__(512, 2) void rnn_kernel(const int* __restrict__ x,
                                                     const int* __restrict__ lengths,
                                                     const float* __restrict__ emb,
                                                     char* __restrict__ ws,
                                                     float* __restrict__ out_) {
    __shared__ __align__(16) _Float16 xhbuf[2][320];

    const int bid  = blockIdx.x;
    const int role = bid >> 6;
    const int b    = bid & 63;
    const int tid  = threadIdx.x;
    const int q    = tid >> 2;
    const int l    = tid & 3;
    const int Q    = 128 * role + q;

    half8_t w[4][9];
    {
        const half8_t* Wp = (const half8_t*)ws + (size_t)role * 36 * 512;
#pragma unroll
        for (int r = 0; r < 4; ++r)
#pragma unroll
            for (int jj = 0; jj < 9; ++jj) w[r][jj] = Wp[(r * 9 + jj) * 512 + tid];
    }
    float4 bs = *(const float4*)(ws + BIAS_OFF + (size_t)Q * 16);

    unsigned int* sexch = (unsigned int*)out_ + (size_t)b * 256;            // SLOW
    unsigned int* fexch = (unsigned int*)(ws + FAST_OFF) + (size_t)b * 256; // FAST
    unsigned int* smine = sexch + role * 128;
    unsigned int* spart = sexch + (1 - role) * 128;
    unsigned int* fmine = fexch + role * 128;
    unsigned int* fpart = fexch + (1 - role) * 128;

    int L = lengths[b];
    if (L > TT) L = TT;
    if (L < 1) L = 1;
    const int* __restrict__ xb = x + b * TT;

    if (tid < 320) xhbuf[0][tid] = (_Float16)0.0f;
    __syncthreads();
    if (tid < EMB) {
        float e0 = emb[xb[0] * EMB + tid];
        xhbuf[0][72 * (tid >> 3) + (tid & 7)] = (_Float16)e0;
    }
    __syncthreads();

    float cc = 0.0f, hh = 0.0f;

    // prologue: own+x partials for step 0
    float p0 = 0.f, p1 = 0.f, p2 = 0.f, p3 = 0.f;
    {
        const _Float16* cur = xhbuf[0];
        half8_t xv[5];
#pragma unroll
        for (int jj = 0; jj < 5; ++jj) xv[jj] = *(const half8_t*)(cur + 72 * l + 8 * jj);
#pragma unroll
        for (int jj = 0; jj < 5; ++jj) {
            p0 = dot8(w[0][jj], xv[jj], p0);
            p1 = dot8(w[1][jj], xv[jj], p1);
            p2 = dot8(w[2][jj], xv[jj], p2);
            p3 = dot8(w[3][jj], xv[jj], p3);
        }
    }

    int mode = 0;            // wave0: 0 = FAST (same-XCD L2), 1 = SLOW (MALL), sticky
    int tok_nxt = (L > 1) ? xb[1] : 0;   // token for step 1 (emb row 0 is zeros)

#pragma unroll 1
    for (int t = 0; t < L; ++t) {
        const _Float16* __restrict__ cur = xhbuf[t & 1];
        _Float16* __restrict__ nxt = xhbuf[(t + 1) & 1];

        // x(t+1) embedding: SINGLE independent load (token carried in regs),
        // fully covered by stage1. Then refill the token pipeline for t+2
        // (wave-uniform scalar load with a whole iteration to land).
        float ev = 0.0f;
        if (tid >= 64 && tid < 64 + EMB)
            ev = emb[tok_nxt * EMB + (tid - 64)];
        tok_nxt = (t + 2 < L) ? xb[t + 2] : 0;

        // 1. partner-col dots (jj 5..8) finish the gate pre-activations
        float a0 = p0, a1 = p1, a2 = p2, a3 = p3;
        {
            half8_t xv[4];
#pragma unroll
            for (int jj = 0; jj < 4; ++jj)
                xv[jj] = *(const half8_t*)(cur + 72 * l + 40 + 8 * jj);
#pragma unroll
            for (int jj = 0; jj < 4; ++jj) {
                a0 = dot8(w[0][5 + jj], xv[jj], a0);
                a1 = dot8(w[1][5 + jj], xv[jj], a1);
                a2 = dot8(w[2][5 + jj], xv[jj], a2);
                a3 = dot8(w[3][5 + jj], xv[jj], a3);
            }
        }

        // 2. reduce + activations
        a0 = quad_reduce(a0);
        a1 = quad_reduce(a1);
        a2 = quad_reduce(a2);
        a3 = quad_reduce(a3);
        float iv = sigmoid_fast(a0 + bs.x);
        float fv = sigmoid_fast(a1 + bs.y);
        float gv = tanh_fast(a2 + bs.z);
        float ov = sigmoid_fast(a3 + bs.w);
        cc = fv * cc + iv * gv;
        hh = ov * tanh_fast(cc);

        const unsigned int tg = ((unsigned)(t + 1) >> 1) & 1u;
        const int ps_ = (t + 1) & 1;

        // 3. dual-publish own h(t+1): FAST plain -> XCD L2; SLOW agent -> MALL
        _Float16 hf = (_Float16)hh;
        unsigned short hb = __builtin_bit_cast(unsigned short, hf);
        unsigned int tb = (unsigned int)((hb & 0xFFFEu) | tg);
        unsigned int nb = (unsigned int)__builtin_amdgcn_mov_dpp((int)tb, 0x104, 0xF, 0xF, true);
        if ((tid & 7) == 0) {
            unsigned int dw = tb | (nb << 16);
            int o = ps_ * 64 + (tid >> 3);
            __hip_atomic_store(fmine + o, dw, __ATOMIC_RELAXED, __HIP_MEMORY_SCOPE_WORKGROUP);
            __hip_atomic_store(smine + o, dw, __ATOMIC_RELAXED, __HIP_MEMORY_SCOPE_AGENT);
        }

        // 4. own-h(t+1) and x(t+1) into next buffer
        if (l == 0) nxt[72 * (q >> 5) + 8 + (q & 31)] = hf;
        if (tid >= 64 && tid < 64 + EMB) {
            int k = tid - 64;
            nxt[72 * (k >> 3) + (k & 7)] = (_Float16)ev;
        }
        barrier_lds();   // A

        // 5. first partner poll, then own+x dots for step t+1 in its shadow
        unsigned int fdw = 0;
        const unsigned int* fp = fpart + ps_ * 64 + tid;
        const unsigned int* sp = spart + ps_ * 64 + tid;
        if (tid < 64) fdw = mode ? load_slow(sp) : load_fast(fp);

        p0 = 0.f; p1 = 0.f; p2 = 0.f; p3 = 0.f;
        {
            half8_t xv[5];
#pragma unroll
            for (int jj = 0; jj < 5; ++jj)
                xv[jj] = *(const half8_t*)(nxt + 72 * l + 8 * jj);
#pragma unroll
            for (int jj = 0; jj < 5; ++jj) {
                p0 = dot8(w[0][jj], xv[jj], p0);
                p1 = dot8(w[1][jj], xv[jj], p1);
                p2 = dot8(w[2][jj], xv[jj], p2);
                p3 = dot8(w[3][jj], xv[jj], p3);
            }
        }

        // 6. wave0: finish the spin (sticky FAST->SLOW), land partner h (b32)
        if (tid < 64) {
            unsigned int dw = fdw;
            int tries = 0;
            while (!__all(((dw & 1u) == tg) && (((dw >> 16) & 1u) == tg))) {
                ++tries;
                if (mode == 0 && tries > 12) mode = 1;  // cross-XCD world: escalate
                if (tries > (1 << 20)) break;
                if (mode) { __builtin_amdgcn_s_sleep(1); dw = load_slow(sp); }
                else      dw = load_fast(fp);
            }
            int j0 = 2 * tid;   // halves j0, j0+1 are LDS-contiguous & b32-aligned
            *(unsigned int*)(&nxt[72 * (j0 >> 5) + 40 + (j0 & 31)]) = dw & 0xFFFEFFFEu;
        }
        barrier_lds();   // B
    }

    // end handshake: partner done reading my d_out region -> safe to overwrite
    int* ack = (int*)(ws + ACK_OFF);
    if (tid == 0)
        __hip_atomic_store(&ack[bid], L, __ATOMIC_RELEASE, __HIP_MEMORY_SCOPE_AGENT);
    if (tid == 0) {
        int tries = 0;
        while (__hip_atomic_load(&ack[bid ^ 64], __ATOMIC_ACQUIRE, __HIP_MEMORY_SCOPE_AGENT) != L) {
            if (++tries > (1 << 20)) break;
            __builtin_amdgcn_s_sleep(8);
        }
    }
    __syncthreads();
    if (l == 0) out_[(size_t)b * 256 + 128 * role + q] = hh;
}

extern "C" void kernel_launch(void* const* d_in, const int* in_sizes, int n_in,
                              void* d_out, int out_size, void* d_ws, size_t ws_size,
                              hipStream_t stream) {
    const int*   x       = (const int*)d_in[0];
    const int*   lengths = (const int*)d_in[1];
    const float* emb     = (const float*)d_in[2];
    const float* W_ih    = (const float*)d_in[3];
    const float* W_hh    = (const float*)d_in[4];
    const float* b_ih    = (const float*)d_in[5];
    const float* b_hh    = (const float*)d_in[6];

    prep_kernel<<<137, 512, 0, stream>>>(W_ih, W_hh, b_ih, b_hh,
                                         (char*)d_ws, (unsigned int*)d_out);
    rnn_kernel<<<128, 512, 0, stream>>>(x, lengths, emb, (char*)d_ws, (float*)d_out);
}